// Round 18
// baseline (208.244 us; speedup 1.0000x reference)
//
#include <hip/hip_runtime.h>
#include <hip/hip_bf16.h>

typedef short bh8 __attribute__((ext_vector_type(8)));      // 8 bf16 (4 VGPR) MFMA frag
typedef float f32x4 __attribute__((ext_vector_type(4)));
typedef float f32x16 __attribute__((ext_vector_type(16)));
typedef float f2 __attribute__((ext_vector_type(2)));
typedef unsigned int uint4v __attribute__((ext_vector_type(4)));

#define GLOBAL_P(p) ((const __attribute__((address_space(1))) void*)(p))
#define LDS_P(p)    ((__attribute__((address_space(3))) void*)(p))

__device__ inline bh8 pack8(const float4& a, const float4& b) {
    union { bh8 v; __hip_bfloat16 h[8]; } u;
    u.h[0] = __float2bfloat16(a.x); u.h[1] = __float2bfloat16(a.y);
    u.h[2] = __float2bfloat16(a.z); u.h[3] = __float2bfloat16(a.w);
    u.h[4] = __float2bfloat16(b.x); u.h[5] = __float2bfloat16(b.y);
    u.h[6] = __float2bfloat16(b.z); u.h[7] = __float2bfloat16(b.w);
    return u.v;
}

// XCD-aware mapping for a 512-block GEMM section (64 bm x 8 bn): keeps one
// A-panel's 8 bn-blocks on ONE XCD (FETCH 141->43MB measured r16->r17).
__device__ __forceinline__ void swz_map(int bid, int& bm, int& bn) {
    const int x = bid & 7, g = bid >> 3;
    bm = ((g >> 3) << 3) | x;
    bn = g & 7;
}

// ---------------------------------------------------------------------------
// prep: fused {q f32->bf16 (blocks 0..4095), W f32->bf16 (4096..6143),
// gather-compact k/v valid rows w/ fused cvt (6144..6655)}.
// ---------------------------------------------------------------------------
__global__ __launch_bounds__(256) void prep(
    const float* __restrict__ q, const float* __restrict__ Wq,
    const float* __restrict__ Wk, const float* __restrict__ Wv,
    const float* __restrict__ Wo, const int* __restrict__ mask,
    const float* __restrict__ kf, const float* __restrict__ vf,
    __hip_bfloat16* __restrict__ qbf, __hip_bfloat16* __restrict__ Wb,
    __hip_bfloat16* __restrict__ kc, __hip_bfloat16* __restrict__ vc,
    int* __restrict__ nv)
{
    __shared__ int ts[256];
    __shared__ int idxL[2048];
    const int bid = blockIdx.x, tid = threadIdx.x;
    if (bid < 4096) {
        size_t i = ((size_t)bid * 256 + tid) * 8;
        float4 x0 = *(const float4*)(q + i), x1 = *(const float4*)(q + i + 4);
        *(bh8*)(qbf + i) = pack8(x0, x1);
    } else if (bid < 6144) {
        const int sb = bid - 4096;
        const int seg = sb >> 9;
        const float* src = (seg == 0) ? Wq : (seg == 1) ? Wk : (seg == 2) ? Wv : Wo;
        size_t i = ((size_t)(sb & 511) * 256 + tid) * 8;
        float4 x0 = *(const float4*)(src + i), x1 = *(const float4*)(src + i + 4);
        *(bh8*)(Wb + (size_t)seg * 1048576 + i) = pack8(x0, x1);
    } else {
        const int gb = bid - 6144;
        const int b = gb >> 7, rb = gb & 127;
        int f[8], cnt = 0;
#pragma unroll
        for (int j = 0; j < 8; ++j) {
            f[j] = (mask[b * 2048 + tid * 8 + j] != 0) ? 1 : 0;
            cnt += f[j];
        }
        ts[tid] = cnt;
        __syncthreads();
        for (int off = 1; off < 256; off <<= 1) {
            int v = (tid >= off) ? ts[tid - off] : 0;
            __syncthreads();
            ts[tid] += v;
            __syncthreads();
        }
        int base = ts[tid] - cnt;   // exclusive prefix
#pragma unroll
        for (int j = 0; j < 8; ++j)
            if (f[j]) idxL[base++] = tid * 8 + j;
        const int n = ts[255];
        if (rb == 0 && tid == 255) nv[b] = n;
        __syncthreads();            // idxL visible to all threads

        const int np = (n + 127) & ~127;
        const int r = rb * 16 + (tid >> 4);
        if (r >= np) return;
        const int c0 = (tid & 15) * 64;
        bh8* dk = (bh8*)(kc + ((size_t)b * 2048 + r) * 1024 + c0);
        bh8* dv = (bh8*)(vc + ((size_t)b * 2048 + r) * 1024 + c0);
        if (r < n) {
            const int s = idxL[r];
            const float4* sk = (const float4*)(kf + ((size_t)b * 2048 + s) * 1024 + c0);
            const float4* sv = (const float4*)(vf + ((size_t)b * 2048 + s) * 1024 + c0);
#pragma unroll
            for (int i = 0; i < 8; ++i) {
                dk[i] = pack8(sk[2 * i], sk[2 * i + 1]);
                dv[i] = pack8(sv[2 * i], sv[2 * i + 1]);
            }
        } else {
            bh8 z = {};
#pragma unroll
            for (int i = 0; i < 8; ++i) { dk[i] = z; dv[i] = z; }
        }
    }
}

// ---------------------------------------------------------------------------
// gemm_core: C[128x128 tile] = (A @ W^T + bias) * oscale.
// T3-min pipeline: double-buffered LDS (As/Bs x2), stage(t+1) issued BEFORE
// compute(t), ONE barrier per K-step (was sync;stage;sync;compute -> load
// latency serially exposed; r17 PMC: MfmaUtil 15%, latency-bound).
// COMPACT: M = 4 batches x 2048; blocks past npad128(batch) exit early.
// ---------------------------------------------------------------------------
template <typename TC, bool COMPACT>
__device__ __forceinline__ void gemm_core(
    const __hip_bfloat16* __restrict__ A, const __hip_bfloat16* __restrict__ W,
    const float* __restrict__ bias, TC* __restrict__ C,
    int N, int Ksz, float oscale, const int* __restrict__ nvp,
    int bm, int bn, __hip_bfloat16* As, __hip_bfloat16* Bs)
{
    if constexpr (COMPACT) {
        const int np = (nvp[bm >> 4] + 127) & ~127;
        if ((bm & 15) * 128 >= np) return;   // whole block exits (no barriers yet)
    }
    const int tid = threadIdx.x;
    const int l = tid & 63, w = tid >> 6;
    const int g4 = l >> 4, rl = l & 15;
    const long m0 = (long)bm * 128, n0 = (long)bn * 128;

    const __hip_bfloat16* ag[4];
    const __hip_bfloat16* wg[4];
    int ldsbase[4];
#pragma unroll
    for (int i = 0; i < 4; ++i) {
        int c = i * 256 + tid;           // chunk 0..1023
        int row = c >> 3, c8 = c & 7;
        ag[i] = A + (m0 + row) * Ksz + c8 * 8;
        wg[i] = W + (n0 + row) * Ksz + c8 * 8;
        ldsbase[i] = (i * 256 + w * 64) * 8;  // wave-uniform glds base (elements)
    }

    const int wr = w >> 1, wc = w & 1;
    f32x4 acc[4][4];
#pragma unroll
    for (int i = 0; i < 4; ++i)
#pragma unroll
        for (int j = 0; j < 4; ++j) acc[i][j] = f32x4{0.f, 0.f, 0.f, 0.f};

    const int nk = Ksz >> 6;
    // prologue: stage tile 0 into buf 0
#pragma unroll
    for (int i = 0; i < 4; ++i) {
        __builtin_amdgcn_global_load_lds(GLOBAL_P(ag[i]), LDS_P(As + ldsbase[i]), 16, 0, 0);
        __builtin_amdgcn_global_load_lds(GLOBAL_P(wg[i]), LDS_P(Bs + ldsbase[i]), 16, 0, 0);
        ag[i] += 64; wg[i] += 64;
    }
    __syncthreads();   // tile 0 staged

    for (int t = 0; t < nk; ++t) {
        const int bo = (t & 1) * 8192;        // compute buffer offset
        const int so = ((t + 1) & 1) * 8192;  // stage buffer offset
        if (t < nk - 1) {                     // issue next tile BEFORE compute
#pragma unroll
            for (int i = 0; i < 4; ++i) {
                __builtin_amdgcn_global_load_lds(GLOBAL_P(ag[i]), LDS_P(As + so + ldsbase[i]), 16, 0, 0);
                __builtin_amdgcn_global_load_lds(GLOBAL_P(wg[i]), LDS_P(Bs + so + ldsbase[i]), 16, 0, 0);
                ag[i] += 64; wg[i] += 64;
            }
        }
#pragma unroll
        for (int kc = 0; kc < 2; ++kc) {
            bh8 af[4], bf[4];
#pragma unroll
            for (int mt = 0; mt < 4; ++mt) {
                int row = wr * 64 + mt * 16 + rl;
                af[mt] = *(const bh8*)(As + bo + row * 64 + 8 * g4 + 32 * kc);
            }
#pragma unroll
            for (int nt = 0; nt < 4; ++nt) {
                int row = wc * 64 + nt * 16 + rl;
                bf[nt] = *(const bh8*)(Bs + bo + row * 64 + 8 * g4 + 32 * kc);
            }
#pragma unroll
            for (int mt = 0; mt < 4; ++mt)
#pragma unroll
                for (int nt = 0; nt < 4; ++nt)
                    acc[mt][nt] = __builtin_amdgcn_mfma_f32_16x16x32_bf16(af[mt], bf[nt], acc[mt][nt], 0, 0, 0);
        }
        __syncthreads();   // drains staged loads + this tile's LDS reads
    }

    // epilogue: (acc + bias) * oscale. C/D: col=lane&15, row=(lane>>4)*4+reg
    float bv[4];
#pragma unroll
    for (int nt = 0; nt < 4; ++nt)
        bv[nt] = bias[n0 + wc * 64 + nt * 16 + rl];
#pragma unroll
    for (int mt = 0; mt < 4; ++mt) {
#pragma unroll
        for (int r = 0; r < 4; ++r) {
            long row = m0 + wr * 64 + mt * 16 + g4 * 4 + r;
            TC* cp = C + row * N + n0 + wc * 64 + rl;
#pragma unroll
            for (int nt = 0; nt < 4; ++nt) {
                float x = (acc[mt][nt][r] + bv[nt]) * oscale;
                if constexpr (__is_same(TC, float)) cp[nt * 16] = x;
                else cp[nt * 16] = __float2bfloat16(x);
            }
        }
    }
}

// Single 512-block GEMM (M=8192, N=1024), XCD-swizzled mapping.
template <typename TC, bool COMPACT>
__global__ __launch_bounds__(256) void gemm_bt(
    const __hip_bfloat16* __restrict__ A, const __hip_bfloat16* __restrict__ W,
    const float* __restrict__ bias, TC* __restrict__ C,
    int N, int Ksz, float oscale, const int* __restrict__ nvp)
{
    __shared__ __hip_bfloat16 As[2 * 128 * 64];
    __shared__ __hip_bfloat16 Bs[2 * 128 * 64];
    int bm, bn;
    swz_map(blockIdx.x, bm, bn);
    gemm_core<TC, COMPACT>(A, W, bias, C, N, Ksz, oscale, nvp, bm, bn, As, Bs);
}

// Fused Q-proj (0..511) + K-proj (512..1023, compact-exit). Fallback path.
__global__ __launch_bounds__(256) void gemm_projqk(
    const __hip_bfloat16* __restrict__ Aq, const __hip_bfloat16* __restrict__ Ak,
    const __hip_bfloat16* __restrict__ Wb, const float* __restrict__ bq,
    const float* __restrict__ bk, __hip_bfloat16* __restrict__ Cq,
    __hip_bfloat16* __restrict__ Ck, const int* __restrict__ nvp, float csc)
{
    __shared__ __hip_bfloat16 As[2 * 128 * 64];
    __shared__ __hip_bfloat16 Bs[2 * 128 * 64];
    const int bid = blockIdx.x;
    int bm, bn;
    if (bid < 512) {
        swz_map(bid, bm, bn);
        gemm_core<__hip_bfloat16, false>(Aq, Wb, bq, Cq, 1024, 1024, csc, nullptr, bm, bn, As, Bs);
    } else {
        swz_map(bid - 512, bm, bn);
        gemm_core<__hip_bfloat16, true>(Ak, Wb + 1048576, bk, Ck, 1024, 1024, 1.0f, nvp, bm, bn, As, Bs);
    }
}

// Fused Q (0..511) + K (512..1023) + V (1024..1535) projections, swizzled.
__global__ __launch_bounds__(256) void gemm_projqkv(
    const __hip_bfloat16* __restrict__ Aq, const __hip_bfloat16* __restrict__ Ak,
    const __hip_bfloat16* __restrict__ Av, const __hip_bfloat16* __restrict__ Wb,
    const float* __restrict__ bq, const float* __restrict__ bk,
    const float* __restrict__ bv, __hip_bfloat16* __restrict__ Cq,
    __hip_bfloat16* __restrict__ Ck, __hip_bfloat16* __restrict__ Cv,
    const int* __restrict__ nvp, float csc)
{
    __shared__ __hip_bfloat16 As[2 * 128 * 64];
    __shared__ __hip_bfloat16 Bs[2 * 128 * 64];
    const int bid = blockIdx.x;
    int bm, bn;
    if (bid < 512) {
        swz_map(bid, bm, bn);
        gemm_core<__hip_bfloat16, false>(Aq, Wb, bq, Cq, 1024, 1024, csc, nullptr, bm, bn, As, Bs);
    } else if (bid < 1024) {
        swz_map(bid - 512, bm, bn);
        gemm_core<__hip_bfloat16, true>(Ak, Wb + 1048576, bk, Ck, 1024, 1024, 1.0f, nvp, bm, bn, As, Bs);
    } else {
        swz_map(bid - 1024, bm, bn);
        gemm_core<__hip_bfloat16, true>(Av, Wb + 2097152, bv, Cv, 1024, 1024, 1.0f, nvp, bm, bn, As, Bs);
    }
}

// ---------------------------------------------------------------------------
// Flash attention over COMPACTED KV (valid columns only, zero-padded to x64).
// B=4 H=16 S=2048 D=64. Q pre-scaled by 0.125*log2(e). r8 structure:
// 4 waves x 32 q-rows (QB=128), KVBLK=64, nt=ceil(nv/64) iters (runtime),
// K via global_load_lds swizzle j^(r&7)^(r>>3); V reg->LDS transpose
// (paired u32 writes). Double-buffered; ONE barrier per iter. Swapped QK^T
// -> in-register softmax (log2, packed f32, half-row l_run, defer-max).
// ---------------------------------------------------------------------------
#define THRL 11.0f                 /* defer-max threshold, log2 units */

__global__ __launch_bounds__(256, 2) void attn_kernel(
    const __hip_bfloat16* __restrict__ Qm, const __hip_bfloat16* __restrict__ Km,
    const __hip_bfloat16* __restrict__ Vm, const int* __restrict__ nvp,
    __hip_bfloat16* __restrict__ Om)
{
    __shared__ __hip_bfloat16 Kt[2][64 * 64];   // K tile double buffer (xor-swizzled slots)
    __shared__ __hip_bfloat16 Vt[2][64 * 64];   // V^T double buffer (swizzled)
    __shared__ float biasS[2048];               // 0 for col<nv, -1e30 for pad
    const int tid = threadIdx.x;
    const int w = tid >> 6, l = tid & 63;
    const int G = l >> 5, c = l & 31;
    // XCD swizzle: xcd = id&7 owns bh = xcd*8 + (slot>>4); qb = slot&15
    const int id = blockIdx.x;
    const int xcd = id & 7, slot = id >> 3;
    const int bh = xcd * 8 + (slot >> 4);
    const int qb = slot & 15;
    const int b = bh >> 4, h = bh & 15;
    const int q0 = qb * 128 + w * 32;

    const int n = nvp[b];
    const int nt = (n + 63) >> 6;

#pragma unroll
    for (int i = 0; i < 8; ++i) {
        int idx = i * 256 + tid;
        biasS[idx] = (idx < n) ? 0.f : -1e30f;
    }

    // Q B-frags: col j = q = c, k = 8G+jj (+16*kc). (Q pre-scaled by CSC.)
    const __hip_bfloat16* qp = Qm + (size_t)(b * 2048 + q0 + c) * 1024 + h * 64 + 8 * G;
    bh8 qf[4];
#pragma unroll
    for (int kc = 0; kc < 4; ++kc) qf[kc] = *(const bh8*)(qp + 16 * kc);

    // K glds: LDS[r][8j] = global[r][8*(j ^ (r&7) ^ (r>>3))].
    const int l38 = l >> 3, lc8 = l & 7;
    const __hip_bfloat16* kg0 = Km + (size_t)(b * 2048 + 16 * w + l38) * 1024 + h * 64 + 8 * ((lc8 ^ l38 ^ (2 * w)) & 7);
    const __hip_bfloat16* kg1 = Km + (size_t)(b * 2048 + 16 * w + 8 + l38) * 1024 + h * 64 + 8 * ((lc8 ^ l38 ^ (2 * w + 1)) & 7);
    const int kbase_e = w * 1024;               // LDS elem base for inst (w,0); (w,1): +512

    // V: thread owns rows {2vpi, 2vpi+1}, d-octet vd0..vd0+7
    const int vpi = tid >> 3, vd0 = (tid & 7) * 8;
    const __hip_bfloat16* vbase = Vm + (size_t)(b * 2048 + 2 * vpi) * 1024 + h * 64 + vd0;

    bh8 va0, va1;   // V rows 2vpi, 2vpi+1 of the prefetched tile
    auto loadV = [&](int tt) {
        const __hip_bfloat16* vp = vbase + (size_t)tt * 64 * 1024;
        va0 = *(const bh8*)vp;
        va1 = *(const bh8*)(vp + 1024);
    };
    auto stageV = [&](int buf) {
        __hip_bfloat16* dst = &Vt[buf][0];
#pragma unroll
        for (int j = 0; j < 8; ++j) {
            int d = vd0 + j;
            int swz = ((d & 7) ^ (d >> 3)) << 3;
            unsigned lo = (unsigned short)((const short*)&va0)[j];
            unsigned hi = (unsigned short)((const short*)&va1)[j];
            *(unsigned*)&dst[(d * 64 + 2 * vpi) ^ swz] = lo | (hi << 16);
        }
    };
    auto stageK = [&](int buf, int tt) {
        const size_t off = (size_t)tt * 64 * 1024;
        __builtin_amdgcn_global_load_lds(GLOBAL_P(kg0 + off), LDS_P(&Kt[buf][0] + kbase_e), 16, 0, 0);
        __builtin_amdgcn_global_load_lds(GLOBAL_P(kg1 + off), LDS_P(&Kt[buf][0] + kbase_e + 512), 16, 0, 0);
    };

    // prologue: K(0)->Kt[0]; V(0)->Vt[0]; V(1)->regs
    stageK(0, 0);
    loadV(0);
    stageV(0);
    loadV(nt > 1 ? 1 : 0);
    __syncthreads();   // drains glds + LDS writes

    f32x16 o0 = {0.f}, o1 = {0.f};
    float m_run = -1e29f, l_run = 0.f;   // l_run is HALF-row (this lane's share)

    for (int t = 0; t < nt; ++t) {
        const int buf = t & 1;
        if (t < nt - 1) {
            stageK(buf ^ 1, t + 1);
            stageV(buf ^ 1);               // va regs hold V(t+1)
            loadV(t + 2 < nt ? t + 2 : nt - 1);
        }
        __builtin_amdgcn_sched_barrier(0);

        // QK^T from LDS: S^T tiles D[i=kv-32ct][j=q], frag rows kv=32ct+c
        const __hip_bfloat16* kbuf = &Kt[buf][0];
        const int kx0 = ((c & 7) ^ (c >> 3)) << 3;   // row c swizzle
        const int kx1 = kx0 ^ 32;                    // row c+32: (r>>3) gains bit 2
        f32x16 s0 = {0.f}, s1 = {0.f};
        __builtin_amdgcn_s_setprio(1);
#pragma unroll
        for (int kc = 0; kc < 4; ++kc) {
            bh8 kf = *(const bh8*)(kbuf + c * 64 + ((16 * kc + 8 * G) ^ kx0));
            s0 = __builtin_amdgcn_mfma_f32_32x32x16_bf16(kf, qf[kc], s0, 0, 0, 0);
        }
#pragma unroll
        for (int kc = 0; kc < 4; ++kc) {
            bh8 kf = *(const bh8*)(kbuf + (c + 32) * 64 + ((16 * kc + 8 * G) ^ kx1));
            s1 = __builtin_amdgcn_mfma_f32_32x32x16_bf16(kf, qf[kc], s1, 0, 0, 0);
        }
        __builtin_amdgcn_s_setprio(0);

        // + pad bias, lane-local max (packed f32); Q already carries scale
        f2 mx2 = {-1e30f, -1e30f};
#pragma unroll
        for (int ct = 0; ct < 2; ++ct) {
            f2* sp = (f2*)(ct ? &s1 : &s0);
#pragma unroll
            for (int i2 = 0; i2 < 8; ++i2) {
                const int i = i2 * 2;
                f2 bb = *(const f2*)&biasS[t * 64 + ct * 32 + (i >> 2) * 8 + 4 * G + (i & 3)];
                f2 sv = sp[i2] + bb;
                sp[i2] = sv;
                mx2 = __builtin_elementwise_max(mx2, sv);
            }
        }
        float mxl = fmaxf(mx2[0], mx2[1]);

        if (__all(mxl - m_run <= THRL)) {
            // defer-max: no rescale, P bounded by 2^THRL
            f2 ls2 = {0.f, 0.f};
            f2 m2 = {m_run, m_run};
#pragma unroll
            for (int ct = 0; ct < 2; ++ct) {
                f2* sp = (f2*)(ct ? &s1 : &s0);
#pragma unroll
                for (int i2 = 0; i2 < 8; ++i2) {
                    f2 e = sp[i2] - m2;
                    f2 p;
                    p[0] = __builtin_amdgcn_exp2f(e[0]);
                    p[1] = __builtin_amdgcn_exp2f(e[1]);
                    sp[i2] = p; ls2 += p;
                }
            }
            l_run += ls2[0] + ls2[1];
        } else {
            float mxf = fmaxf(mxl, __shfl_xor(mxl, 32));
            const float m_new = fmaxf(m_run, mxf);
            const float fac = __builtin_amdgcn_exp2f(m_run - m_new);
            f2 ls2 = {0.f, 0.f};
            f2 m2 = {m_new, m_new};
#pragma unroll
            for (int ct = 0; ct < 2; ++ct) {
                f2* sp = (f2*)(ct ? &s1 : &s0);
#pragma unroll
                for (int i2 = 0; i2 < 8; ++i2) {
                    f2 e = sp[i2] - m2;
                    f2 p;
                    p[0] = __builtin_amdgcn_exp2f(e[0]);
                    p[1] = __builtin_amdgcn_exp2f(e[1]);
                    sp[i2] = p; ls2 += p;
                }
            }
            l_run = l_run * fac + (ls2[0] + ls2[1]);
            m_run = m_new;
            f2 fc = {fac, fac};
            f2* o0p = (f2*)&o0; f2* o1p = (f2*)&o1;
#pragma unroll
            for (int i2 = 0; i2 < 8; ++i2) { o0p[i2] *= fc; o1p[i2] *= fc; }
        }

        // PV: O^T += mfma(V^T-frag, P^T-frag). P^T frag built in-register.
        const __hip_bfloat16* vbuf = &Vt[buf][0];
        const int swz0 = ((c & 7) ^ (c >> 3)) << 3;
        const int swz1 = ((c & 7) ^ ((c + 32) >> 3)) << 3;
#pragma unroll
        for (int sl = 0; sl < 4; ++sl) {
            const f32x16& ps = (sl < 2) ? s0 : s1;
            const int R0 = 8 * (sl & 1);
            unsigned a0, a1, b0, b1;
            asm("v_cvt_pk_bf16_f32 %0, %1, %2" : "=v"(a0) : "v"(ps[R0 + 0]), "v"(ps[R0 + 1]));
            asm("v_cvt_pk_bf16_f32 %0, %1, %2" : "=v"(a1) : "v"(ps[R0 + 2]), "v"(ps[R0 + 3]));
            asm("v_cvt_pk_bf16_f32 %0, %1, %2" : "=v"(b0) : "v"(ps[R0 + 4]), "v"(ps[R0 + 5]));
            asm("v_cvt_pk_bf16_f32 %0, %1, %2" : "=v"(b1) : "v"(ps[R0 + 6]), "v"(ps[R0 + 7]));
            asm("v_permlane32_swap_b32 %0, %1" : "+v"(a0), "+v"(b0));
            asm("v_permlane32_swap_b32 %0, %1" : "+v"(a1), "+v"(b1));
            uint4v pu = {a0, a1, b0, b1};
            bh8 pf = __builtin_bit_cast(bh8, pu);
            const int kvb = 16 * sl + 8 * G;
            bh8 vf0 = *(const bh8*)(vbuf + c * 64 + (kvb ^ swz0));
            bh8 vf1 = *(const bh8*)(vbuf + (c + 32) * 64 + (kvb ^ swz1));
            __builtin_amdgcn_s_setprio(1);
            o0 = __builtin_amdgcn_mfma_f32_32x32x16_bf16(vf0, pf, o0, 0, 0, 0);
            o1 = __builtin_amdgcn_mfma_f32_32x32x16_bf16(vf1, pf, o1, 0, 0, 0);
            __builtin_amdgcn_s_setprio(0);
        }

        __syncthreads();   // buf reads done; buf^1 staging drained
    }

    // epilogue: combine half-row sums, O = acc/l (l==0 -> 0), packed stores
    float l_tot = l_run + __shfl_xor(l_run, 32);
    float inv = (l_tot > 0.f) ? 1.f / l_tot : 0.f;
    __hip_bfloat16* op = Om + (size_t)(b * 2048 + q0 + c) * 1024 + h * 64 + 4 * G;
#pragma unroll
    for (int dt = 0; dt < 2; ++dt) {
#pragma unroll
        for (int rb = 0; rb < 4; ++rb) {
            union { ushort4 u; __hip_bfloat16 hv[4]; } cv;
#pragma unroll
            for (int j = 0; j < 4; ++j) {
                float x = (dt ? o1[rb * 4 + j] : o0[rb * 4 + j]) * inv;
                cv.hv[j] = __float2bfloat16(x);
            }
            *(ushort4*)(op + dt * 32 + rb * 8) = cv.u;
        }
    }
}

// ---------------------------------------------------------------------------
extern "C" void kernel_launch(void* const* d_in, const int* in_sizes, int n_in,
                              void* d_out, int out_size, void* d_ws, size_t ws_size,
                              hipStream_t stream) {
    const float* q  = (const float*)d_in[0];
    const float* k  = (const float*)d_in[1];
    const float* v  = (const float*)d_in[2];
    const int*   mk = (const int*)d_in[3];
    const float* Wq = (const float*)d_in[4];
    const float* bq = (const float*)d_in[5];
    const float* Wk = (const float*)d_in[6];
    const float* bk = (const float*)d_in[7];
    const float* Wv = (const float*)d_in[8];
    const float* bv = (const float*)d_in[9];
    const float* Wo = (const float*)d_in[10];
    const float* bo = (const float*)d_in[11];
    float* out = (float*)d_out;

    const float CSC = 0.18033688011112042f;      // 0.125 * log2(e), folded into Q
    const size_t MN = (size_t)8192 * 1024;
    const size_t WN = (size_t)1024 * 1024;
    __hip_bfloat16* R0 = (__hip_bfloat16*)d_ws;  // q_bf  -> Ow (attn out)
    __hip_bfloat16* R1 = R0 + MN;                // kc_in (-> Vc in fallback)
    __hip_bfloat16* R2 = R1 + MN;                // vc_in
    __hip_bfloat16* R3 = R2 + MN;                // Qw (pre-scaled)
    __hip_bfloat16* Wb = R3 + MN;                // Wq,Wk,Wv,Wo bf16 (4 x 1M elems)
    int* nvp = (int*)(Wb + 4 * WN);              // [4] valid counts
    __hip_bfloat16* R4 = (__hip_bfloat16*)((char*)nvp + 256);   // Kc (K-proj out)
    __hip_bfloat16* R5 = R4 + MN;                                // Vc (fused path only)
    const size_t need = (size_t)((char*)(R5 + MN) - (char*)d_ws);

    prep<<<6656, 256, 0, stream>>>(q, Wq, Wk, Wv, Wo, mk, k, v, R0, Wb, R1, R2, nvp);
    if (ws_size >= need) {
        // fused 4-dispatch path
        gemm_projqkv<<<1536, 256, 0, stream>>>(R0, R1, R2, Wb, bq, bk, bv, R3, R4, R5, nvp, CSC);
        attn_kernel<<<1024, 256, 0, stream>>>(R3, R4, R5, nvp, R0);
    } else {
        // fallback (r15-proven footprint): V-proj separate, Vc overwrites R1
        gemm_projqk<<<1024, 256, 0, stream>>>(R0, R1, Wb, bq, bk, R3, R4, nvp, CSC);
        gemm_bt<__hip_bfloat16, true><<<512, 256, 0, stream>>>(R2, Wb + 2 * WN, bv, R1, 1024, 1024, 1.0f, nvp);
        attn_kernel<<<1024, 256, 0, stream>>>(R3, R4, R1, nvp, R0);
    }
    gemm_bt<float, false><<<512, 256, 0, stream>>>(R0, Wb + 3 * WN, bo, out, 1024, 1024, 1.0f, nullptr);
}

// Round 19
// 203.403 us; speedup vs baseline: 1.0238x; 1.0238x over previous
//
#include <hip/hip_runtime.h>
#include <hip/hip_bf16.h>

typedef short bh8 __attribute__((ext_vector_type(8)));      // 8 bf16 (4 VGPR) MFMA frag
typedef float f32x4 __attribute__((ext_vector_type(4)));
typedef float f32x16 __attribute__((ext_vector_type(16)));
typedef float f2 __attribute__((ext_vector_type(2)));
typedef unsigned int uint4v __attribute__((ext_vector_type(4)));

#define GLOBAL_P(p) ((const __attribute__((address_space(1))) void*)(p))
#define LDS_P(p)    ((__attribute__((address_space(3))) void*)(p))

__device__ inline bh8 pack8(const float4& a, const float4& b) {
    union { bh8 v; __hip_bfloat16 h[8]; } u;
    u.h[0] = __float2bfloat16(a.x); u.h[1] = __float2bfloat16(a.y);
    u.h[2] = __float2bfloat16(a.z); u.h[3] = __float2bfloat16(a.w);
    u.h[4] = __float2bfloat16(b.x); u.h[5] = __float2bfloat16(b.y);
    u.h[6] = __float2bfloat16(b.z); u.h[7] = __float2bfloat16(b.w);
    return u.v;
}

// ---------------------------------------------------------------------------
// prep: fused {q f32->bf16 (blocks 0..4095), W f32->bf16 (4096..6143),
// maskScan (6144..6147)}.
// ---------------------------------------------------------------------------
__global__ __launch_bounds__(256) void prep(
    const float* __restrict__ q, const float* __restrict__ Wq,
    const float* __restrict__ Wk, const float* __restrict__ Wv,
    const float* __restrict__ Wo, const int* __restrict__ mask,
    __hip_bfloat16* __restrict__ qbf, __hip_bfloat16* __restrict__ Wb,
    int* __restrict__ idx, int* __restrict__ nv)
{
    __shared__ int ts[256];
    const int bid = blockIdx.x, tid = threadIdx.x;
    if (bid < 4096) {
        size_t i = ((size_t)bid * 256 + tid) * 8;
        float4 x0 = *(const float4*)(q + i), x1 = *(const float4*)(q + i + 4);
        *(bh8*)(qbf + i) = pack8(x0, x1);
    } else if (bid < 6144) {
        const int sb = bid - 4096;
        const int seg = sb >> 9;
        const float* src = (seg == 0) ? Wq : (seg == 1) ? Wk : (seg == 2) ? Wv : Wo;
        size_t i = ((size_t)(sb & 511) * 256 + tid) * 8;
        float4 x0 = *(const float4*)(src + i), x1 = *(const float4*)(src + i + 4);
        *(bh8*)(Wb + (size_t)seg * 1048576 + i) = pack8(x0, x1);
    } else {
        const int b = bid - 6144;
        int f[8], cnt = 0;
#pragma unroll
        for (int j = 0; j < 8; ++j) {
            f[j] = (mask[b * 2048 + tid * 8 + j] != 0) ? 1 : 0;
            cnt += f[j];
        }
        ts[tid] = cnt;
        __syncthreads();
        for (int off = 1; off < 256; off <<= 1) {
            int v = (tid >= off) ? ts[tid - off] : 0;
            __syncthreads();
            ts[tid] += v;
            __syncthreads();
        }
        int base = ts[tid] - cnt;   // exclusive prefix
#pragma unroll
        for (int j = 0; j < 8; ++j)
            if (f[j]) idx[b * 2048 + base++] = tid * 8 + j;
        if (tid == 255) nv[b] = ts[255];
    }
}

// ---------------------------------------------------------------------------
// gatherTok: compact VALID k,v token rows (f32 source, fused cvt to bf16);
// zero-pad rows [n, npad128). Grid 512 = 4b x 128 row-blocks (16 rows each),
// 16 threads/row, 64 f32/thread per tensor.
// ---------------------------------------------------------------------------
__global__ __launch_bounds__(256) void gatherTok(
    const float* __restrict__ kf, const float* __restrict__ vf,
    const int* __restrict__ idx, const int* __restrict__ nv,
    __hip_bfloat16* __restrict__ kc, __hip_bfloat16* __restrict__ vc)
{
    const int b = blockIdx.x >> 7, rb = blockIdx.x & 127;
    const int n = nv[b], np = (n + 127) & ~127;
    const int r = rb * 16 + (threadIdx.x >> 4);
    if (r >= np) return;
    const int c0 = (threadIdx.x & 15) * 64;
    bh8* dk = (bh8*)(kc + ((size_t)b * 2048 + r) * 1024 + c0);
    bh8* dv = (bh8*)(vc + ((size_t)b * 2048 + r) * 1024 + c0);
    if (r < n) {
        const int s = idx[b * 2048 + r];
        const float4* sk = (const float4*)(kf + ((size_t)b * 2048 + s) * 1024 + c0);
        const float4* sv = (const float4*)(vf + ((size_t)b * 2048 + s) * 1024 + c0);
#pragma unroll
        for (int i = 0; i < 8; ++i) {
            dk[i] = pack8(sk[2 * i], sk[2 * i + 1]);
            dv[i] = pack8(sv[2 * i], sv[2 * i + 1]);
        }
    } else {
        bh8 z = {};
#pragma unroll
        for (int i = 0; i < 8; ++i) { dk[i] = z; dv[i] = z; }
    }
}

// ---------------------------------------------------------------------------
// gemm_core: C[128x128 tile] = (A @ W^T + bias) * oscale. m97 structure.
// COMPACT: M = 4 batches x 2048; blocks past npad128(batch) exit early.
// ---------------------------------------------------------------------------
template <typename TC, bool COMPACT>
__device__ __forceinline__ void gemm_core(
    const __hip_bfloat16* __restrict__ A, const __hip_bfloat16* __restrict__ W,
    const float* __restrict__ bias, TC* __restrict__ C,
    int N, int Ksz, float oscale, const int* __restrict__ nvp,
    int bm, int bn, __hip_bfloat16* As, __hip_bfloat16* Bs)
{
    if constexpr (COMPACT) {
        const int np = (nvp[bm >> 4] + 127) & ~127;
        if ((bm & 15) * 128 >= np) return;   // whole block exits (no barriers yet)
    }
    const int tid = threadIdx.x;
    const int l = tid & 63, w = tid >> 6;
    const int g4 = l >> 4, rl = l & 15;
    const long m0 = (long)bm * 128, n0 = (long)bn * 128;

    const __hip_bfloat16* ag[4];
    const __hip_bfloat16* wg[4];
    int ldsbase[4];
#pragma unroll
    for (int i = 0; i < 4; ++i) {
        int c = i * 256 + tid;           // chunk 0..1023
        int row = c >> 3, c8 = c & 7;
        ag[i] = A + (m0 + row) * Ksz + c8 * 8;
        wg[i] = W + (n0 + row) * Ksz + c8 * 8;
        ldsbase[i] = (i * 256 + w * 64) * 8;  // wave-uniform glds base (elements)
    }

    const int wr = w >> 1, wc = w & 1;
    f32x4 acc[4][4];
#pragma unroll
    for (int i = 0; i < 4; ++i)
#pragma unroll
        for (int j = 0; j < 4; ++j) acc[i][j] = f32x4{0.f, 0.f, 0.f, 0.f};

    const int nk = Ksz >> 6;
    for (int t = 0; t < nk; ++t) {
        __syncthreads();   // previous tile's LDS reads complete
#pragma unroll
        for (int i = 0; i < 4; ++i) {
            __builtin_amdgcn_global_load_lds(GLOBAL_P(ag[i]), LDS_P(As + ldsbase[i]), 16, 0, 0);
            __builtin_amdgcn_global_load_lds(GLOBAL_P(wg[i]), LDS_P(Bs + ldsbase[i]), 16, 0, 0);
            ag[i] += 64; wg[i] += 64;
        }
        __syncthreads();   // staged (barrier drains vmcnt)
#pragma unroll
        for (int kc = 0; kc < 2; ++kc) {
            bh8 af[4], bf[4];
#pragma unroll
            for (int mt = 0; mt < 4; ++mt) {
                int row = wr * 64 + mt * 16 + rl;
                af[mt] = *(const bh8*)(As + row * 64 + 8 * g4 + 32 * kc);
            }
#pragma unroll
            for (int nt = 0; nt < 4; ++nt) {
                int row = wc * 64 + nt * 16 + rl;
                bf[nt] = *(const bh8*)(Bs + row * 64 + 8 * g4 + 32 * kc);
            }
#pragma unroll
            for (int mt = 0; mt < 4; ++mt)
#pragma unroll
                for (int nt = 0; nt < 4; ++nt)
                    acc[mt][nt] = __builtin_amdgcn_mfma_f32_16x16x32_bf16(af[mt], bf[nt], acc[mt][nt], 0, 0, 0);
        }
    }

    // epilogue: (acc + bias) * oscale. C/D: col=lane&15, row=(lane>>4)*4+reg
    float bv[4];
#pragma unroll
    for (int nt = 0; nt < 4; ++nt)
        bv[nt] = bias[n0 + wc * 64 + nt * 16 + rl];
#pragma unroll
    for (int mt = 0; mt < 4; ++mt) {
#pragma unroll
        for (int r = 0; r < 4; ++r) {
            long row = m0 + wr * 64 + mt * 16 + g4 * 4 + r;
            TC* cp = C + row * N + n0 + wc * 64 + rl;
#pragma unroll
            for (int nt = 0; nt < 4; ++nt) {
                float x = (acc[mt][nt][r] + bv[nt]) * oscale;
                if constexpr (__is_same(TC, float)) cp[nt * 16] = x;
                else cp[nt * 16] = __float2bfloat16(x);
            }
        }
    }
}

template <typename TC, bool COMPACT>
__global__ __launch_bounds__(256) void gemm_bt(
    const __hip_bfloat16* __restrict__ A, const __hip_bfloat16* __restrict__ W,
    const float* __restrict__ bias, TC* __restrict__ C,
    int N, int Ksz, float oscale, const int* __restrict__ nvp)
{
    __shared__ __hip_bfloat16 As[128 * 64];
    __shared__ __hip_bfloat16 Bs[128 * 64];
    const int nb = N >> 7;
    gemm_core<TC, COMPACT>(A, W, bias, C, N, Ksz, oscale, nvp,
                           blockIdx.x / nb, blockIdx.x % nb, As, Bs);
}

// Fused Q-proj (blocks 0..511) + K-proj (blocks 512..1023, compact-exit).
__global__ __launch_bounds__(256) void gemm_projqk(
    const __hip_bfloat16* __restrict__ Aq, const __hip_bfloat16* __restrict__ Ak,
    const __hip_bfloat16* __restrict__ Wb, const float* __restrict__ bq,
    const float* __restrict__ bk, __hip_bfloat16* __restrict__ Cq,
    __hip_bfloat16* __restrict__ Ck, const int* __restrict__ nvp, float csc)
{
    __shared__ __hip_bfloat16 As[128 * 64];
    __shared__ __hip_bfloat16 Bs[128 * 64];
    const int bid = blockIdx.x;
    if (bid < 512)
        gemm_core<__hip_bfloat16, false>(Aq, Wb, bq, Cq, 1024, 1024, csc, nullptr,
                                         bid >> 3, bid & 7, As, Bs);
    else
        gemm_core<__hip_bfloat16, true>(Ak, Wb + 1048576, bk, Ck, 1024, 1024, 1.0f, nvp,
                                        (bid - 512) >> 3, bid & 7, As, Bs);
}

// ---------------------------------------------------------------------------
// Flash attention over COMPACTED KV (valid columns only, zero-padded to x64).
// B=4 H=16 S=2048 D=64. Q pre-scaled by 0.125*log2(e). r8 structure:
// 4 waves x 32 q-rows (QB=128), KVBLK=64, nt=ceil(nv/64) iters (runtime),
// K via global_load_lds swizzle j^(r&7)^(r>>3); V reg->LDS transpose
// (paired u32 writes). Double-buffered; ONE barrier per iter. Swapped QK^T
// -> in-register softmax (log2, packed f32, half-row l_run, defer-max).
// Pad cols get bias -1e30 -> P=0 exactly (pad K/V rows = finite bias vecs).
// nt==0 (all-masked batch): loop skipped, l=0 -> O=0 (matches reference).
// ---------------------------------------------------------------------------
#define THRL 11.0f                 /* defer-max threshold, log2 units */

__global__ __launch_bounds__(256, 2) void attn_kernel(
    const __hip_bfloat16* __restrict__ Qm, const __hip_bfloat16* __restrict__ Km,
    const __hip_bfloat16* __restrict__ Vm, const int* __restrict__ nvp,
    __hip_bfloat16* __restrict__ Om)
{
    __shared__ __hip_bfloat16 Kt[2][64 * 64];   // K tile double buffer (xor-swizzled slots)
    __shared__ __hip_bfloat16 Vt[2][64 * 64];   // V^T double buffer (swizzled)
    __shared__ float biasS[2048];               // 0 for col<nv, -1e30 for pad
    const int tid = threadIdx.x;
    const int w = tid >> 6, l = tid & 63;
    const int G = l >> 5, c = l & 31;
    // XCD swizzle: xcd = id&7 owns bh = xcd*8 + (slot>>4); qb = slot&15
    const int id = blockIdx.x;
    const int xcd = id & 7, slot = id >> 3;
    const int bh = xcd * 8 + (slot >> 4);
    const int qb = slot & 15;
    const int b = bh >> 4, h = bh & 15;
    const int q0 = qb * 128 + w * 32;

    const int n = nvp[b];
    const int nt = (n + 63) >> 6;

#pragma unroll
    for (int i = 0; i < 8; ++i) {
        int idx = i * 256 + tid;
        biasS[idx] = (idx < n) ? 0.f : -1e30f;
    }

    // Q B-frags: col j = q = c, k = 8G+jj (+16*kc). (Q pre-scaled by CSC.)
    const __hip_bfloat16* qp = Qm + (size_t)(b * 2048 + q0 + c) * 1024 + h * 64 + 8 * G;
    bh8 qf[4];
#pragma unroll
    for (int kc = 0; kc < 4; ++kc) qf[kc] = *(const bh8*)(qp + 16 * kc);

    // K glds: LDS[r][8j] = global[r][8*(j ^ (r&7) ^ (r>>3))].
    // inst (w,i): rows r = 16w+8i+(l>>3); r&7 = l>>3, r>>3 = 2w+i (uniform).
    const int l38 = l >> 3, lc8 = l & 7;
    const __hip_bfloat16* kg0 = Km + (size_t)(b * 2048 + 16 * w + l38) * 1024 + h * 64 + 8 * ((lc8 ^ l38 ^ (2 * w)) & 7);
    const __hip_bfloat16* kg1 = Km + (size_t)(b * 2048 + 16 * w + 8 + l38) * 1024 + h * 64 + 8 * ((lc8 ^ l38 ^ (2 * w + 1)) & 7);
    const int kbase_e = w * 1024;               // LDS elem base for inst (w,0); (w,1): +512

    // V: thread owns rows {2vpi, 2vpi+1}, d-octet vd0..vd0+7
    const int vpi = tid >> 3, vd0 = (tid & 7) * 8;
    const __hip_bfloat16* vbase = Vm + (size_t)(b * 2048 + 2 * vpi) * 1024 + h * 64 + vd0;

    bh8 va0, va1;   // V rows 2vpi, 2vpi+1 of the prefetched tile
    auto loadV = [&](int tt) {
        const __hip_bfloat16* vp = vbase + (size_t)tt * 64 * 1024;
        va0 = *(const bh8*)vp;
        va1 = *(const bh8*)(vp + 1024);
    };
    auto stageV = [&](int buf) {
        __hip_bfloat16* dst = &Vt[buf][0];
#pragma unroll
        for (int j = 0; j < 8; ++j) {
            int d = vd0 + j;
            int swz = ((d & 7) ^ (d >> 3)) << 3;
            unsigned lo = (unsigned short)((const short*)&va0)[j];
            unsigned hi = (unsigned short)((const short*)&va1)[j];
            *(unsigned*)&dst[(d * 64 + 2 * vpi) ^ swz] = lo | (hi << 16);
        }
    };
    auto stageK = [&](int buf, int tt) {
        const size_t off = (size_t)tt * 64 * 1024;
        __builtin_amdgcn_global_load_lds(GLOBAL_P(kg0 + off), LDS_P(&Kt[buf][0] + kbase_e), 16, 0, 0);
        __builtin_amdgcn_global_load_lds(GLOBAL_P(kg1 + off), LDS_P(&Kt[buf][0] + kbase_e + 512), 16, 0, 0);
    };

    // prologue: K(0)->Kt[0]; V(0)->Vt[0]; V(1)->regs (clamped; in-bounds since
    // the compact buffer spans 2048 rows)
    stageK(0, 0);
    loadV(0);
    stageV(0);
    loadV(nt > 1 ? 1 : 0);
    __syncthreads();   // drains glds + LDS writes

    f32x16 o0 = {0.f}, o1 = {0.f};
    float m_run = -1e29f, l_run = 0.f;   // l_run is HALF-row (this lane's share)

    for (int t = 0; t < nt; ++t) {
        const int buf = t & 1;
        // stage next tile into buf^1; prefetch V(t+2) into regs
        if (t < nt - 1) {
            stageK(buf ^ 1, t + 1);
            stageV(buf ^ 1);               // va regs hold V(t+1)
            loadV(t + 2 < nt ? t + 2 : nt - 1);
        }
        __builtin_amdgcn_sched_barrier(0);

        // QK^T from LDS: S^T tiles D[i=kv-32ct][j=q], frag rows kv=32ct+c
        const __hip_bfloat16* kbuf = &Kt[buf][0];
        const int kx0 = ((c & 7) ^ (c >> 3)) << 3;   // row c swizzle
        const int kx1 = kx0 ^ 32;                    // row c+32: (r>>3) gains bit 2
        f32x16 s0 = {0.f}, s1 = {0.f};
        __builtin_amdgcn_s_setprio(1);
#pragma unroll
        for (int kc = 0; kc < 4; ++kc) {
            bh8 kf = *(const bh8*)(kbuf + c * 64 + ((16 * kc + 8 * G) ^ kx0));
            s0 = __builtin_amdgcn_mfma_f32_32x32x16_bf16(kf, qf[kc], s0, 0, 0, 0);
        }
#pragma unroll
        for (int kc = 0; kc < 4; ++kc) {
            bh8 kf = *(const bh8*)(kbuf + (c + 32) * 64 + ((16 * kc + 8 * G) ^ kx1));
            s1 = __builtin_amdgcn_mfma_f32_32x32x16_bf16(kf, qf[kc], s1, 0, 0, 0);
        }
        __builtin_amdgcn_s_setprio(0);

        // + pad bias, lane-local max (packed f32); Q already carries scale
        f2 mx2 = {-1e30f, -1e30f};
#pragma unroll
        for (int ct = 0; ct < 2; ++ct) {
            f2* sp = (f2*)(ct ? &s1 : &s0);
#pragma unroll
            for (int i2 = 0; i2 < 8; ++i2) {
                const int i = i2 * 2;
                f2 bb = *(const f2*)&biasS[t * 64 + ct * 32 + (i >> 2) * 8 + 4 * G + (i & 3)];
                f2 sv = sp[i2] + bb;
                sp[i2] = sv;
                mx2 = __builtin_elementwise_max(mx2, sv);
            }
        }
        float mxl = fmaxf(mx2[0], mx2[1]);

        if (__all(mxl - m_run <= THRL)) {
            // defer-max: no rescale, P bounded by 2^THRL
            f2 ls2 = {0.f, 0.f};
            f2 m2 = {m_run, m_run};
#pragma unroll
            for (int ct = 0; ct < 2; ++ct) {
                f2* sp = (f2*)(ct ? &s1 : &s0);
#pragma unroll
                for (int i2 = 0; i2 < 8; ++i2) {
                    f2 e = sp[i2] - m2;
                    f2 p;
                    p[0] = __builtin_amdgcn_exp2f(e[0]);
                    p[1] = __builtin_amdgcn_exp2f(e[1]);
                    sp[i2] = p; ls2 += p;
                }
            }
            l_run += ls2[0] + ls2[1];
        } else {
            float mxf = fmaxf(mxl, __shfl_xor(mxl, 32));
            const float m_new = fmaxf(m_run, mxf);
            const float fac = __builtin_amdgcn_exp2f(m_run - m_new);
            f2 ls2 = {0.f, 0.f};
            f2 m2 = {m_new, m_new};
#pragma unroll
            for (int ct = 0; ct < 2; ++ct) {
                f2* sp = (f2*)(ct ? &s1 : &s0);
#pragma unroll
                for (int i2 = 0; i2 < 8; ++i2) {
                    f2 e = sp[i2] - m2;
                    f2 p;
                    p[0] = __builtin_amdgcn_exp2f(e[0]);
                    p[1] = __builtin_amdgcn_exp2f(e[1]);
                    sp[i2] = p; ls2 += p;
                }
            }
            l_run = l_run * fac + (ls2[0] + ls2[1]);
            m_run = m_new;
            f2 fc = {fac, fac};
            f2* o0p = (f2*)&o0; f2* o1p = (f2*)&o1;
#pragma unroll
            for (int i2 = 0; i2 < 8; ++i2) { o0p[i2] *= fc; o1p[i2] *= fc; }
        }

        // PV: O^T += mfma(V^T-frag, P^T-frag). P^T frag built in-register.
        const __hip_bfloat16* vbuf = &Vt[buf][0];
        const int swz0 = ((c & 7) ^ (c >> 3)) << 3;
        const int swz1 = ((c & 7) ^ ((c + 32) >> 3)) << 3;
#pragma unroll
        for (int sl = 0; sl < 4; ++sl) {
            const f32x16& ps = (sl < 2) ? s0 : s1;
            const int R0 = 8 * (sl & 1);
            unsigned a0, a1, b0, b1;
            asm("v_cvt_pk_bf16_f32 %0, %1, %2" : "=v"(a0) : "v"(ps[R0 + 0]), "v"(ps[R0 + 1]));
            asm("v_cvt_pk_bf16_f32 %0, %1, %2" : "=v"(a1) : "v"(ps[R0 + 2]), "v"(ps[R0 + 3]));
            asm("v_cvt_pk_bf16_f32 %0, %1, %2" : "=v"(b0) : "v"(ps[R0 + 4]), "v"(ps[R0 + 5]));
            asm("v_cvt_pk_bf16_f32 %0, %1, %2" : "=v"(b1) : "v"(ps[R0 + 6]), "v"(ps[R0 + 7]));
            asm("v_permlane32_swap_b32 %0, %1" : "+v"(a0), "+v"(b0));
            asm("v_permlane32_swap_b32 %0, %1" : "+v"(a1), "+v"(b1));
            uint4v pu = {a0, a1, b0, b1};
            bh8 pf = __builtin_bit_cast(bh8, pu);
            const int kvb = 16 * sl + 8 * G;
            bh8 vf0 = *(const bh8*)(vbuf + c * 64 + (kvb ^ swz0));
            bh8 vf1 = *(const bh8*)(vbuf + (c + 32) * 64 + (kvb ^ swz1));
            __builtin_amdgcn_s_setprio(1);
            o0 = __builtin_amdgcn_mfma_f32_32x32x16_bf16(vf0, pf, o0, 0, 0, 0);
            o1 = __builtin_amdgcn_mfma_f32_32x32x16_bf16(vf1, pf, o1, 0, 0, 0);
            __builtin_amdgcn_s_setprio(0);
        }

        __syncthreads();   // buf reads done; buf^1 staging drained
    }

    // epilogue: combine half-row sums, O = acc/l (l==0 -> 0), packed stores
    float l_tot = l_run + __shfl_xor(l_run, 32);
    float inv = (l_tot > 0.f) ? 1.f / l_tot : 0.f;
    __hip_bfloat16* op = Om + (size_t)(b * 2048 + q0 + c) * 1024 + h * 64 + 4 * G;
#pragma unroll
    for (int dt = 0; dt < 2; ++dt) {
#pragma unroll
        for (int rb = 0; rb < 4; ++rb) {
            union { ushort4 u; __hip_bfloat16 hv[4]; } cv;
#pragma unroll
            for (int j = 0; j < 4; ++j) {
                float x = (dt ? o1[rb * 4 + j] : o0[rb * 4 + j]) * inv;
                cv.hv[j] = __float2bfloat16(x);
            }
            *(ushort4*)(op + dt * 32 + rb * 8) = cv.u;
        }
    }
}

// ---------------------------------------------------------------------------
extern "C" void kernel_launch(void* const* d_in, const int* in_sizes, int n_in,
                              void* d_out, int out_size, void* d_ws, size_t ws_size,
                              hipStream_t stream) {
    const float* q  = (const float*)d_in[0];
    const float* k  = (const float*)d_in[1];
    const float* v  = (const float*)d_in[2];
    const int*   mk = (const int*)d_in[3];
    const float* Wq = (const float*)d_in[4];
    const float* bq = (const float*)d_in[5];
    const float* Wk = (const float*)d_in[6];
    const float* bk = (const float*)d_in[7];
    const float* Wv = (const float*)d_in[8];
    const float* bv = (const float*)d_in[9];
    const float* Wo = (const float*)d_in[10];
    const float* bo = (const float*)d_in[11];
    float* out = (float*)d_out;

    const float CSC = 0.18033688011112042f;      // 0.125 * log2(e), folded into Q
    const size_t MN = (size_t)8192 * 1024;
    const size_t WN = (size_t)1024 * 1024;
    // Region plan (~92 MB, r15-proven):
    __hip_bfloat16* R0 = (__hip_bfloat16*)d_ws;  // q_bf  -> Ow (attn out)
    __hip_bfloat16* R1 = R0 + MN;                // kc_in -> Vc (V-proj out)
    __hip_bfloat16* R2 = R1 + MN;                // vc_in
    __hip_bfloat16* R3 = R2 + MN;                // Qw (pre-scaled)
    __hip_bfloat16* Wb = R3 + MN;                // Wq,Wk,Wv,Wo bf16 (4 x 1M elems)
    int* idxp = (int*)(Wb + 4 * WN);             // [4][2048] compact indices
    int* nvp  = idxp + 4 * 2048;                 // [4] valid counts
    __hip_bfloat16* R4 = (__hip_bfloat16*)((char*)idxp + 33024);  // Kc (K-proj out)

    prep<<<6148, 256, 0, stream>>>(q, Wq, Wk, Wv, Wo, mk, R0, Wb, idxp, nvp);
    gatherTok<<<512, 256, 0, stream>>>(k, v, idxp, nvp, R1, R2);              // kc_in=R1, vc_in=R2
    gemm_projqk<<<1024, 256, 0, stream>>>(R0, R1, Wb, bq, bk, R3, R4, nvp, CSC); // Qw=R3, Kc=R4
    gemm_bt<__hip_bfloat16, true><<<512, 256, 0, stream>>>(R2, Wb + 2 * WN, bv, R1, 1024, 1024, 1.0f, nvp); // Vc=R1
    attn_kernel<<<1024, 256, 0, stream>>>(R3, R4, R1, nvp, R0);               // Ow=R0
    gemm_bt<float, false><<<512, 256, 0, stream>>>(R0, Wb + 3 * WN, bo, out, 1024, 1024, 1.0f, nullptr);
}